// Round 3
// baseline (2663.371 us; speedup 1.0000x reference)
//
#include <hip/hip_runtime.h>
#include <hip/hip_bf16.h>
#include <stdint.h>

// ---------------------------------------------------------------------------
// LSTM: B=64, S=512, D_IN=1024, HID=4096, HS=1024, fp32 in/out.
//   1) cvt x, wx, wh -> bf16
//   2) pregemm (MFMA bf16, 128x128 tile): xg2 = x@wx.T + bx + bh, bf16,
//      recurrence-friendly layout [t][wg][bloc][n]  (identical to R3)
//   3) persistent recurrent kernel, R6: SELF-VALIDATING TAGGED h exchange.
//      Same decomposition as proven R3 (4 groups x 16 batches x 64 slices,
//      wh fragments register-resident, all cross-WG traffic sc0+sc1 LLC).
//      Protocol change: h' is stored as ONE dword (tag<<16 | bf16(h)) where
//      tag = t+1. Consumers poll the DATA directly: retry-load all 64 h
//      dwords per lane until min(high16) == t. Tag and value share a dword
//      -> atomically self-consistent, ZERO store-ordering assumptions.
//      This deletes per step: the flag-observe LLC RT, the producer's
//      pre-flag vmcnt(0) store-ack + barrier + flag store. WAR safety:
//      wave kq's tag-checked loads fully cover producer slices
//      [kq*16,kq*16+16); the 4 waves jointly cover all 64 group WGs and
//      join at the gpart __syncthreads before any h' write; a fresh tag
//      from WG X implies X passed its barrier => finished reading the
//      buffer being overwritten. Second barrier after elementwise protects
//      gpart WAR across iterations.
//      Also: xg2 prefetched one step ahead (plain loads, compiler waits);
//      tagged hbuf32 (512 KB) reuses the dead xbf region, zeroed AFTER
//      pregemm (stream-ordered) -> workspace size unchanged.
// R3 fix retained: register-tied s_waitcnt between asm h-loads and use.
// ---------------------------------------------------------------------------

typedef __attribute__((ext_vector_type(8))) short short8;
typedef __attribute__((ext_vector_type(4))) float floatx4;
typedef __attribute__((ext_vector_type(4))) unsigned int uintx4;

#define S_LEN 512
#define BATCH 64
#define DIN   1024
#define HID   4096
#define HS    1024

// workspace byte offsets (total ~336.3 MB, same footprint as R3)
#define XG2_OFF   0ull                      // ushort[512*256*16*64] = 256 MB
#define XBF_OFF   268435456ull              // ushort[32768*1024]    = 64 MB
#define WXBF_OFF  335544320ull              // ushort[4096*1024]     = 8 MB
#define WHBF_OFF  343932928ull              // ushort[4096*1024]     = 8 MB
// tagged h buffer: uint[2][64][1024] = 512 KB, aliases the FIRST 512 KB of
// the xbf region (xbf is dead after pregemm; zeroed after pregemm runs).
#define HBUF32_OFF XBF_OFF

__device__ __forceinline__ unsigned short f2bf(float f) {
  unsigned int u = __float_as_uint(f);
  u += 0x7fffu + ((u >> 16) & 1u);        // RNE
  return (unsigned short)(u >> 16);
}
__device__ __forceinline__ float bf2f(unsigned short s) {
  return __uint_as_float(((unsigned int)s) << 16);
}
__device__ __forceinline__ unsigned int umin_(unsigned int a, unsigned int b) {
  return a < b ? a : b;
}

__device__ __forceinline__ void async_ld16(const void* g, const void* l) {
  __builtin_amdgcn_global_load_lds(
      (const __attribute__((address_space(1))) unsigned int*)g,
      (__attribute__((address_space(3))) unsigned int*)l,
      16, 0, 0);
}

// LLC-coherent (sc0 sc1) dword store: write-through to LLC, fire-and-forget.
__device__ __forceinline__ void st4_llc(void* p, unsigned int v) {
  asm volatile("global_store_dword %0, %1, off sc0 sc1"
               :: "v"(p), "v"(v) : "memory");
}

__device__ __forceinline__ float sigmoidf_(float x) {
  return 1.0f / (1.0f + __expf(-x));
}
__device__ __forceinline__ float tanhf_(float x) {
  return 2.0f / (1.0f + __expf(-2.0f * x)) - 1.0f;
}

// --------------------------- fp32 -> bf16 cast ------------------------------
__global__ void cvt_kernel(const float* __restrict__ src,
                           unsigned short* __restrict__ dst, int n4) {
  int i = blockIdx.x * blockDim.x + threadIdx.x;
  if (i < n4) {
    float4 v = ((const float4*)src)[i];
    ushort4 o;
    o.x = f2bf(v.x); o.y = f2bf(v.y); o.z = f2bf(v.z); o.w = f2bf(v.w);
    ((ushort4*)dst)[i] = o;
  }
}

__global__ void zero_kernel(unsigned int* __restrict__ p, int n) {
  int i = blockIdx.x * blockDim.x + threadIdx.x;
  if (i < n) p[i] = 0u;
}

// ------------------------------- pre-GEMM -----------------------------------
// C[m][g] = sum_k x_bf[m][k] * wx_bf[g][k] + bx[g] + bh[g]   (m = b*512 + t)
// stored bf16 at xg2[((t*256 + wg)*16 + bloc)*64 + n],
//   wg = (b>>4)*64 + ((g&1023)>>4),  bloc = b&15,  n = (g>>10)*16 + (g&15)
// (identical to R3's proven kernel)
__global__ __launch_bounds__(256) void pregemm_kernel(
    const unsigned short* __restrict__ A,    // [32768][1024] bf16
    const unsigned short* __restrict__ Bw,   // [4096][1024]  bf16 (B^T layout)
    const float* __restrict__ bx, const float* __restrict__ bh,
    unsigned short* __restrict__ xg2) {
  __shared__ unsigned short As[128 * 32];
  __shared__ unsigned short Bs[128 * 32];
  const int tid = threadIdx.x;
  const int lane = tid & 63, wv = tid >> 6;
  const int l15 = lane & 15, lq = lane >> 4;
  const int m0 = blockIdx.y * 128, n0 = blockIdx.x * 128;
  const int wm = (wv >> 1) * 64, wn = (wv & 1) * 64;

  floatx4 acc[4][4];
#pragma unroll
  for (int i = 0; i < 4; i++)
#pragma unroll
    for (int j = 0; j < 4; j++) acc[i][j] = (floatx4){0.f, 0.f, 0.f, 0.f};

  for (int k0 = 0; k0 < DIN; k0 += 32) {
#pragma unroll
    for (int q = 0; q < 2; q++) {
      const int e = (q * 256 + tid) * 8;      // element within 128x32 tile
      const int r = e >> 5, c = e & 31;
      async_ld16(A + (size_t)(m0 + r) * DIN + k0 + c, (unsigned short*)As + e);
      async_ld16(Bw + (size_t)(n0 + r) * DIN + k0 + c, (unsigned short*)Bs + e);
    }
    __syncthreads();
    short8 af[4], bfv[4];
#pragma unroll
    for (int i = 0; i < 4; i++)
      af[i] = *(const short8*)&As[(wm + i * 16 + l15) * 32 + lq * 8];
#pragma unroll
    for (int j = 0; j < 4; j++)
      bfv[j] = *(const short8*)&Bs[(wn + j * 16 + l15) * 32 + lq * 8];
#pragma unroll
    for (int i = 0; i < 4; i++)
#pragma unroll
      for (int j = 0; j < 4; j++)
        acc[i][j] = __builtin_amdgcn_mfma_f32_16x16x32_bf16(af[i], bfv[j],
                                                            acc[i][j], 0, 0, 0);
    __syncthreads();
  }

#pragma unroll
  for (int j = 0; j < 4; j++) {
    const int col = n0 + wn + j * 16 + l15;
    const float bias = bx[col] + bh[col];
    const int gate = col >> 10;
    const int c1 = col & 1023;
    const int wslice = c1 >> 4, cc = c1 & 15;
    const int n_idx = gate * 16 + cc;
#pragma unroll
    for (int i = 0; i < 4; i++) {
#pragma unroll
      for (int r = 0; r < 4; r++) {
        const int m = m0 + wm + i * 16 + lq * 4 + r;
        const int b = m >> 9, t = m & 511;
        const size_t idx =
            ((size_t)(t * 256 + ((b >> 4) * 64 + wslice)) * 16 + (b & 15)) * 64 +
            n_idx;
        xg2[idx] = f2bf(acc[i][j][r] + bias);
      }
    }
  }
}

// ------------------------------ recurrence ----------------------------------
// 256 WGs = 4 groups x 64 slices (R3 decomposition). Group g handles batches
// [g*16, g*16+16). WG slice w holds wh rows {gate*1024 + w*16 + c} in
// registers (4 waves split K: wave kq holds k in [kq*256, kq*256+256)).
// h exchange: tagged dwords through LLC (sc0 sc1), self-validating.
__global__ __launch_bounds__(256, 1) void lstm_kernel(
    const unsigned short* __restrict__ whbf,  // [4096][1024] bf16
    const unsigned short* __restrict__ xg2,
    unsigned int* __restrict__ hbuf32,        // [2][64][1024] tagged dwords
    float* __restrict__ out,                  // [64][512][1024]
    float* __restrict__ outh, float* __restrict__ outc) {
  __shared__ float gpart[4 * 16 * 68];  // [kq][bloc][n] padded

  const int tid = threadIdx.x;
  const int lane = tid & 63, kq = tid >> 6;
  const int l15 = lane & 15, lq = lane >> 4;
  const int wg = blockIdx.x;
  const int group = wg >> 6, wslice = wg & 63;
  const int j0 = wslice * 16;

  // B fragments: bfrag[j][kc] covers gate j, cols j0..j0+15, k = kq*256+kc*32+..
  short8 bfrag[4][8];
#pragma unroll
  for (int j = 0; j < 4; j++) {
    const size_t grow = (size_t)(j * 1024 + j0 + l15) * HS;
#pragma unroll
    for (int kc = 0; kc < 8; kc++)
      bfrag[j][kc] = *(const short8*)&whbf[grow + kq * 256 + kc * 32 + lq * 8];
  }

  const int eb = tid >> 4;         // bloc 0..15 (elementwise phase)
  const int ec = tid & 15;         // col within slice
  const int gb = group * 16 + eb;  // global batch
  float c_state = 0.0f;

  // h-load base (dword units): batch group*16+l15, col kq*256 + lq*8 (+kc*32)
  const size_t arow = (size_t)(group * 16 + l15) * HS + kq * 256 + lq * 8;

  // xg for t=0
  const unsigned short* xr0 = xg2 + ((size_t)(0 * 256 + wg) * 16 + eb) * 64 + ec;
  unsigned short xv0 = xr0[0], xv1 = xr0[16], xv2 = xr0[32], xv3 = xr0[48];

  for (int t = 0; t < S_LEN; t++) {
    uintx4 qa[16];
    if (t > 0) {
      // retry-load tagged h until every dword carries tag == t.
      // Coverage: this wave's 64 lanes x 64 dwords span the FULL output of
      // producer slices [kq*16, kq*16+16) (16 batches x cols kq*256..+256).
      const unsigned int* hp = hbuf32 + (size_t)(t & 1) * (BATCH * HS) + arow;
      while (true) {
#pragma unroll
        for (int kc = 0; kc < 8; kc++) {
          asm volatile("global_load_dwordx4 %0, %1, off sc0 sc1"
                       : "=v"(qa[2 * kc]) : "v"(hp + kc * 32) : "memory");
          asm volatile("global_load_dwordx4 %0, %1, off sc0 sc1"
                       : "=v"(qa[2 * kc + 1]) : "v"(hp + kc * 32 + 4) : "memory");
        }
        // Register-tied drain (R3 discipline): consumers below data-depend on
        // post-wait values, so they cannot be hoisted above the waitcnt.
        asm volatile("s_waitcnt vmcnt(0)"
                     : "+v"(qa[0]), "+v"(qa[1]), "+v"(qa[2]), "+v"(qa[3]),
                       "+v"(qa[4]), "+v"(qa[5]), "+v"(qa[6]), "+v"(qa[7])
                     :: "memory");
        asm volatile(""
                     : "+v"(qa[8]), "+v"(qa[9]), "+v"(qa[10]), "+v"(qa[11]),
                       "+v"(qa[12]), "+v"(qa[13]), "+v"(qa[14]), "+v"(qa[15])
                     :: "memory");
        unsigned int mn = 0xffffffffu;
#pragma unroll
        for (int i = 0; i < 16; i++) {
          unsigned int m1 = umin_(umin_(qa[i].x, qa[i].y),
                                  umin_(qa[i].z, qa[i].w));
          mn = umin_(mn, m1);
        }
        if (__all((int)(mn >> 16) == t)) break;  // all fresh
        __builtin_amdgcn_s_sleep(1);
      }
    } else {
#pragma unroll
      for (int i = 0; i < 16; i++) qa[i] = (uintx4){0u, 0u, 0u, 0u};
    }

    // Prefetch next step's xg (plain loads; compiler inserts waits at use in
    // the NEXT iteration -- latency hidden under MFMA + elementwise + poll).
    // At t = S_LEN-1 this reads past xg2 into workspace (values unused).
    const unsigned short* xb =
        xg2 + ((size_t)((t + 1) * 256 + wg) * 16 + eb) * 64 + ec;
    unsigned short nx0 = xb[0], nx1 = xb[16], nx2 = xb[32], nx3 = xb[48];

    // pack tagged dwords -> bf16 short8 fragments (low16 of each dword)
    short8 a[8];
#pragma unroll
    for (int kc = 0; kc < 8; kc++) {
      const uintx4 lo = qa[2 * kc], hi = qa[2 * kc + 1];
      uintx4 w;
      w.x = __builtin_amdgcn_perm(lo.y, lo.x, 0x05040100u);
      w.y = __builtin_amdgcn_perm(lo.w, lo.z, 0x05040100u);
      w.z = __builtin_amdgcn_perm(hi.y, hi.x, 0x05040100u);
      w.w = __builtin_amdgcn_perm(hi.w, hi.z, 0x05040100u);
      a[kc] = __builtin_bit_cast(short8, w);
    }

    floatx4 acc0 = (floatx4){0.f, 0.f, 0.f, 0.f};
    floatx4 acc1 = acc0, acc2 = acc0, acc3 = acc0;
#pragma unroll
    for (int kc = 0; kc < 8; kc++) {
      acc0 = __builtin_amdgcn_mfma_f32_16x16x32_bf16(a[kc], bfrag[0][kc], acc0, 0, 0, 0);
      acc1 = __builtin_amdgcn_mfma_f32_16x16x32_bf16(a[kc], bfrag[1][kc], acc1, 0, 0, 0);
      acc2 = __builtin_amdgcn_mfma_f32_16x16x32_bf16(a[kc], bfrag[2][kc], acc2, 0, 0, 0);
      acc3 = __builtin_amdgcn_mfma_f32_16x16x32_bf16(a[kc], bfrag[3][kc], acc3, 0, 0, 0);
    }
#pragma unroll
    for (int r = 0; r < 4; r++) {
      const int row = (kq * 16 + lq * 4 + r) * 68;
      gpart[row + 0 * 16 + l15] = acc0[r];
      gpart[row + 1 * 16 + l15] = acc1[r];
      gpart[row + 2 * 16 + l15] = acc2[r];
      gpart[row + 3 * 16 + l15] = acc3[r];
    }
    __syncthreads();  // joint tag-validation cover (all 4 waves) + gpart ready

    float g0 = bf2f(xv0), g1 = bf2f(xv1), g2 = bf2f(xv2), g3 = bf2f(xv3);
#pragma unroll
    for (int q = 0; q < 4; q++) {
      const float* gp = &gpart[(q * 16 + eb) * 68 + ec];
      g0 += gp[0]; g1 += gp[16]; g2 += gp[32]; g3 += gp[48];
    }
    const float i_ = sigmoidf_(g0);
    const float f_ = sigmoidf_(g1);
    const float gg = tanhf_(g2);
    const float o_ = sigmoidf_(g3);
    c_state = f_ * c_state + i_ * gg;
    const float h = o_ * tanhf_(c_state);

    // tagged h' write-through to LLC: fire-and-forget (tag t+1 validates it)
    st4_llc(&hbuf32[(size_t)((t + 1) & 1) * (BATCH * HS) + (size_t)gb * HS +
                    j0 + ec],
            (((unsigned int)(t + 1)) << 16) | (unsigned int)f2bf(h));

    if (t == S_LEN - 1) {
      out[((size_t)gb * S_LEN + t) * HS + j0 + ec] = h;
      outh[gb * HS + j0 + ec] = h;
      outc[gb * HS + j0 + ec] = c_state;
      break;
    }

    // out store: nontemporal, fully off the critical path (drained by the
    // next step's retry-loop vmcnt(0)).
    __builtin_nontemporal_store(h, &out[((size_t)gb * S_LEN + t) * HS + j0 + ec]);

    __syncthreads();  // gpart WAR across iterations

    xv0 = nx0; xv1 = nx1; xv2 = nx2; xv3 = nx3;
  }
}

// ------------------------------- launcher -----------------------------------
extern "C" void kernel_launch(void* const* d_in, const int* in_sizes, int n_in,
                              void* d_out, int out_size, void* d_ws,
                              size_t ws_size, hipStream_t stream) {
  const float* x  = (const float*)d_in[0];
  const float* wx = (const float*)d_in[1];
  const float* wh = (const float*)d_in[2];
  const float* bx = (const float*)d_in[3];
  const float* bh = (const float*)d_in[4];
  char* ws = (char*)d_ws;
  unsigned short* xg2  = (unsigned short*)(ws + XG2_OFF);
  unsigned short* xbf  = (unsigned short*)(ws + XBF_OFF);
  unsigned short* wxbf = (unsigned short*)(ws + WXBF_OFF);
  unsigned short* whbf = (unsigned short*)(ws + WHBF_OFF);
  unsigned int*   hbuf32 = (unsigned int*)(ws + HBUF32_OFF);

  float* out  = (float*)d_out;
  float* outh = out + (size_t)BATCH * S_LEN * HS;
  float* outc = outh + BATCH * HS;

  cvt_kernel<<<(33554432 / 4) / 256, 256, 0, stream>>>(x, xbf, 33554432 / 4);
  cvt_kernel<<<(4194304 / 4) / 256, 256, 0, stream>>>(wx, wxbf, 4194304 / 4);
  cvt_kernel<<<(4194304 / 4) / 256, 256, 0, stream>>>(wh, whbf, 4194304 / 4);

  dim3 pg(HID / 128, (BATCH * S_LEN) / 128);  // 32 x 256
  pregemm_kernel<<<pg, 256, 0, stream>>>(xbf, wxbf, bx, bh, xg2);

  // zero tagged hbuf (131072 dwords) AFTER pregemm: it aliases the first
  // 512 KB of the (now dead) xbf region. Stream order guarantees safety.
  zero_kernel<<<(131072 + 255) / 256, 256, 0, stream>>>(hbuf32, 131072);

  lstm_kernel<<<256, 256, 0, stream>>>(whbf, xg2, hbuf32, out, outh, outc);
}

// Round 4
// 2467.662 us; speedup vs baseline: 1.0793x; 1.0793x over previous
//
#include <hip/hip_runtime.h>
#include <hip/hip_bf16.h>
#include <stdint.h>

// ---------------------------------------------------------------------------
// LSTM: B=64, S=512, D_IN=1024, HID=4096, HS=1024, fp32 in/out.
//   1) cvt x, wx, wh -> bf16
//   2) pregemm (MFMA bf16, 128x128 tile): xg2 = x@wx.T + bx + bh, bf16,
//      recurrence-friendly layout [t][wg][bloc][n]  (identical to R3)
//   3) persistent recurrent kernel, R7: HINT-FLAG + TAGGED-DATA hybrid.
//      R3 decomposition (4 groups x 16 batches x 64 slices, wh register-
//      resident, all cross-WG traffic sc0+sc1 LLC). h' stored as tagged
//      dwords (tag<<16 | bf16) -- fire-and-forget, self-validating (R6,
//      proven). NEW vs R6: per-WG hint flag stored by tid0 with NO store
//      drain / NO barrier / NO ordering; consumers do R3's cheap 64B flag
//      poll first, then ONE tagged data round (verify tags; rare re-load if
//      flag raced ahead of data). This restores cheap poll rounds (R6's
//      regression: every poll round was a fat 32KB/wave data load) while
//      keeping R6's deletion of the producer-side vmcnt(0)+barrier+ordered-
//      flag chain (R3's cost). Correctness rests ONLY on tags:
//      a dword's tag and payload are atomically consistent; wave kq's
//      verified loads cover producer slices [kq*16,kq*16+16) completely;
//      4 waves jointly cover all 64 group WGs and join at the gpart
//      __syncthreads before any h' write => a WG cannot write tag t+1 over
//      a buffer some reader still needs at tag t-1 (writer would first have
//      to observe ALL tags t, including that reader's own step-t output,
//      which is emitted only after its reads complete). Flags are hints.
//      xg2 prefetched one step ahead (plain loads; latency lands in the
//      producer-wait window). Tagged hbuf32 (512 KB) aliases the dead xbf
//      region, zeroed AFTER pregemm (stream-ordered).
// R3 fix retained: register-tied s_waitcnt between asm h-loads and use.
// ---------------------------------------------------------------------------

typedef __attribute__((ext_vector_type(8))) short short8;
typedef __attribute__((ext_vector_type(4))) float floatx4;
typedef __attribute__((ext_vector_type(4))) unsigned int uintx4;

#define S_LEN 512
#define BATCH 64
#define DIN   1024
#define HID   4096
#define HS    1024

// workspace byte offsets (total ~336.3 MB, same footprint as R3)
#define XG2_OFF   0ull                      // ushort[512*256*16*64] = 256 MB
#define XBF_OFF   268435456ull              // ushort[32768*1024]    = 64 MB
#define WXBF_OFF  335544320ull              // ushort[4096*1024]     = 8 MB
#define WHBF_OFF  343932928ull              // ushort[4096*1024]     = 8 MB
#define FLAG_OFF  352583680ull              // int[256*16]           = 16 KB
// tagged h buffer: uint[2][64][1024] = 512 KB, aliases the FIRST 512 KB of
// the xbf region (xbf is dead after pregemm; zeroed after pregemm runs).
#define HBUF32_OFF XBF_OFF

__device__ __forceinline__ unsigned short f2bf(float f) {
  unsigned int u = __float_as_uint(f);
  u += 0x7fffu + ((u >> 16) & 1u);        // RNE
  return (unsigned short)(u >> 16);
}
__device__ __forceinline__ float bf2f(unsigned short s) {
  return __uint_as_float(((unsigned int)s) << 16);
}
__device__ __forceinline__ unsigned int umin_(unsigned int a, unsigned int b) {
  return a < b ? a : b;
}

__device__ __forceinline__ void async_ld16(const void* g, const void* l) {
  __builtin_amdgcn_global_load_lds(
      (const __attribute__((address_space(1))) unsigned int*)g,
      (__attribute__((address_space(3))) unsigned int*)l,
      16, 0, 0);
}

// LLC-coherent (sc0 sc1) dword store: write-through to LLC, fire-and-forget.
__device__ __forceinline__ void st4_llc(void* p, unsigned int v) {
  asm volatile("global_store_dword %0, %1, off sc0 sc1"
               :: "v"(p), "v"(v) : "memory");
}
// LLC-coherent dword load with embedded drain (flag poll).
__device__ __forceinline__ int ld_flag_llc(const int* p) {
  int v;
  asm volatile("global_load_dword %0, %1, off sc0 sc1\n\t"
               "s_waitcnt vmcnt(0)"
               : "=v"(v) : "v"(p) : "memory");
  return v;
}

__device__ __forceinline__ float sigmoidf_(float x) {
  return 1.0f / (1.0f + __expf(-x));
}
__device__ __forceinline__ float tanhf_(float x) {
  return 2.0f / (1.0f + __expf(-2.0f * x)) - 1.0f;
}

// --------------------------- fp32 -> bf16 cast ------------------------------
__global__ void cvt_kernel(const float* __restrict__ src,
                           unsigned short* __restrict__ dst, int n4) {
  int i = blockIdx.x * blockDim.x + threadIdx.x;
  if (i < n4) {
    float4 v = ((const float4*)src)[i];
    ushort4 o;
    o.x = f2bf(v.x); o.y = f2bf(v.y); o.z = f2bf(v.z); o.w = f2bf(v.w);
    ((ushort4*)dst)[i] = o;
  }
}

__global__ void zero_kernel(unsigned int* __restrict__ p, int n) {
  int i = blockIdx.x * blockDim.x + threadIdx.x;
  if (i < n) p[i] = 0u;
}

// ------------------------------- pre-GEMM -----------------------------------
// C[m][g] = sum_k x_bf[m][k] * wx_bf[g][k] + bx[g] + bh[g]   (m = b*512 + t)
// stored bf16 at xg2[((t*256 + wg)*16 + bloc)*64 + n],
//   wg = (b>>4)*64 + ((g&1023)>>4),  bloc = b&15,  n = (g>>10)*16 + (g&15)
// (identical to R3's proven kernel)
__global__ __launch_bounds__(256) void pregemm_kernel(
    const unsigned short* __restrict__ A,    // [32768][1024] bf16
    const unsigned short* __restrict__ Bw,   // [4096][1024]  bf16 (B^T layout)
    const float* __restrict__ bx, const float* __restrict__ bh,
    unsigned short* __restrict__ xg2) {
  __shared__ unsigned short As[128 * 32];
  __shared__ unsigned short Bs[128 * 32];
  const int tid = threadIdx.x;
  const int lane = tid & 63, wv = tid >> 6;
  const int l15 = lane & 15, lq = lane >> 4;
  const int m0 = blockIdx.y * 128, n0 = blockIdx.x * 128;
  const int wm = (wv >> 1) * 64, wn = (wv & 1) * 64;

  floatx4 acc[4][4];
#pragma unroll
  for (int i = 0; i < 4; i++)
#pragma unroll
    for (int j = 0; j < 4; j++) acc[i][j] = (floatx4){0.f, 0.f, 0.f, 0.f};

  for (int k0 = 0; k0 < DIN; k0 += 32) {
#pragma unroll
    for (int q = 0; q < 2; q++) {
      const int e = (q * 256 + tid) * 8;      // element within 128x32 tile
      const int r = e >> 5, c = e & 31;
      async_ld16(A + (size_t)(m0 + r) * DIN + k0 + c, (unsigned short*)As + e);
      async_ld16(Bw + (size_t)(n0 + r) * DIN + k0 + c, (unsigned short*)Bs + e);
    }
    __syncthreads();
    short8 af[4], bfv[4];
#pragma unroll
    for (int i = 0; i < 4; i++)
      af[i] = *(const short8*)&As[(wm + i * 16 + l15) * 32 + lq * 8];
#pragma unroll
    for (int j = 0; j < 4; j++)
      bfv[j] = *(const short8*)&Bs[(wn + j * 16 + l15) * 32 + lq * 8];
#pragma unroll
    for (int i = 0; i < 4; i++)
#pragma unroll
      for (int j = 0; j < 4; j++)
        acc[i][j] = __builtin_amdgcn_mfma_f32_16x16x32_bf16(af[i], bfv[j],
                                                            acc[i][j], 0, 0, 0);
    __syncthreads();
  }

#pragma unroll
  for (int j = 0; j < 4; j++) {
    const int col = n0 + wn + j * 16 + l15;
    const float bias = bx[col] + bh[col];
    const int gate = col >> 10;
    const int c1 = col & 1023;
    const int wslice = c1 >> 4, cc = c1 & 15;
    const int n_idx = gate * 16 + cc;
#pragma unroll
    for (int i = 0; i < 4; i++) {
#pragma unroll
      for (int r = 0; r < 4; r++) {
        const int m = m0 + wm + i * 16 + lq * 4 + r;
        const int b = m >> 9, t = m & 511;
        const size_t idx =
            ((size_t)(t * 256 + ((b >> 4) * 64 + wslice)) * 16 + (b & 15)) * 64 +
            n_idx;
        xg2[idx] = f2bf(acc[i][j][r] + bias);
      }
    }
  }
}

// ------------------------------ recurrence ----------------------------------
// 256 WGs = 4 groups x 64 slices (R3 decomposition). Group g handles batches
// [g*16, g*16+16). WG slice w holds wh rows {gate*1024 + w*16 + c} in
// registers (4 waves split K: wave kq holds k in [kq*256, kq*256+256)).
__global__ __launch_bounds__(256, 1) void lstm_kernel(
    const unsigned short* __restrict__ whbf,  // [4096][1024] bf16
    const unsigned short* __restrict__ xg2,
    unsigned int* __restrict__ hbuf32,        // [2][64][1024] tagged dwords
    int* __restrict__ flags,                  // [256*16] hint flags
    float* __restrict__ out,                  // [64][512][1024]
    float* __restrict__ outh, float* __restrict__ outc) {
  __shared__ float gpart[4 * 16 * 68];  // [kq][bloc][n] padded

  const int tid = threadIdx.x;
  const int lane = tid & 63, kq = tid >> 6;
  const int l15 = lane & 15, lq = lane >> 4;
  const int wg = blockIdx.x;
  const int group = wg >> 6, wslice = wg & 63;
  const int j0 = wslice * 16;

  // B fragments: bfrag[j][kc] covers gate j, cols j0..j0+15, k = kq*256+kc*32+..
  short8 bfrag[4][8];
#pragma unroll
  for (int j = 0; j < 4; j++) {
    const size_t grow = (size_t)(j * 1024 + j0 + l15) * HS;
#pragma unroll
    for (int kc = 0; kc < 8; kc++)
      bfrag[j][kc] = *(const short8*)&whbf[grow + kq * 256 + kc * 32 + lq * 8];
  }

  const int eb = tid >> 4;         // bloc 0..15 (elementwise phase)
  const int ec = tid & 15;         // col within slice
  const int gb = group * 16 + eb;  // global batch
  float c_state = 0.0f;

  // h-load base (dword units): batch group*16+l15, col kq*256 + lq*8 (+kc*32)
  const size_t arow = (size_t)(group * 16 + l15) * HS + kq * 256 + lq * 8;
  // wave kq consumes h cols [kq*256, kq*256+256) -> producer WGs kq*16..+16
  const int* fp = flags + (size_t)(group * 64 + kq * 16 + l15) * 16;

  // xg for t=0
  const unsigned short* xr0 = xg2 + ((size_t)(0 * 256 + wg) * 16 + eb) * 64 + ec;
  unsigned short xv0 = xr0[0], xv1 = xr0[16], xv2 = xr0[32], xv3 = xr0[48];

  for (int t = 0; t < S_LEN; t++) {
    uintx4 qa[16];
    if (t > 0) {
      // 1) cheap hint-flag poll (64B rounds; 16 lanes active per wave)
      while (true) {
        int v = t;
        if (lq == 0) v = ld_flag_llc(fp);
        if (__all(v >= t)) break;
        __builtin_amdgcn_s_sleep(1);
      }
      // 2) tagged data load + verify (expected: exactly one round)
      const unsigned int* hp = hbuf32 + (size_t)(t & 1) * (BATCH * HS) + arow;
      while (true) {
#pragma unroll
        for (int kc = 0; kc < 8; kc++) {
          asm volatile("global_load_dwordx4 %0, %1, off sc0 sc1"
                       : "=v"(qa[2 * kc]) : "v"(hp + kc * 32) : "memory");
          asm volatile("global_load_dwordx4 %0, %1, off sc0 sc1"
                       : "=v"(qa[2 * kc + 1]) : "v"(hp + kc * 32 + 4) : "memory");
        }
        // Register-tied drain (R3 discipline): consumers below data-depend on
        // post-wait values, so they cannot be hoisted above the waitcnt.
        asm volatile("s_waitcnt vmcnt(0)"
                     : "+v"(qa[0]), "+v"(qa[1]), "+v"(qa[2]), "+v"(qa[3]),
                       "+v"(qa[4]), "+v"(qa[5]), "+v"(qa[6]), "+v"(qa[7])
                     :: "memory");
        asm volatile(""
                     : "+v"(qa[8]), "+v"(qa[9]), "+v"(qa[10]), "+v"(qa[11]),
                       "+v"(qa[12]), "+v"(qa[13]), "+v"(qa[14]), "+v"(qa[15])
                     :: "memory");
        unsigned int mn = 0xffffffffu;
#pragma unroll
        for (int i = 0; i < 16; i++) {
          unsigned int m1 = umin_(umin_(qa[i].x, qa[i].y),
                                  umin_(qa[i].z, qa[i].w));
          mn = umin_(mn, m1);
        }
        if (__all((int)(mn >> 16) == t)) break;  // all fresh
        __builtin_amdgcn_s_sleep(1);
      }
    } else {
#pragma unroll
      for (int i = 0; i < 16; i++) qa[i] = (uintx4){0u, 0u, 0u, 0u};
    }

    // Prefetch next step's xg (plain loads; compiler-inserted waits land in
    // the NEXT iteration's poll window -- HBM latency off the chain).
    // At t = S_LEN-1 this reads past xg2 into workspace (values unused).
    const unsigned short* xb =
        xg2 + ((size_t)((t + 1) * 256 + wg) * 16 + eb) * 64 + ec;
    unsigned short nx0 = xb[0], nx1 = xb[16], nx2 = xb[32], nx3 = xb[48];

    // pack tagged dwords -> bf16 short8 fragments (low16 of each dword)
    short8 a[8];
#pragma unroll
    for (int kc = 0; kc < 8; kc++) {
      const uintx4 lo = qa[2 * kc], hi = qa[2 * kc + 1];
      uintx4 w;
      w.x = __builtin_amdgcn_perm(lo.y, lo.x, 0x05040100u);
      w.y = __builtin_amdgcn_perm(lo.w, lo.z, 0x05040100u);
      w.z = __builtin_amdgcn_perm(hi.y, hi.x, 0x05040100u);
      w.w = __builtin_amdgcn_perm(hi.w, hi.z, 0x05040100u);
      a[kc] = __builtin_bit_cast(short8, w);
    }

    floatx4 acc0 = (floatx4){0.f, 0.f, 0.f, 0.f};
    floatx4 acc1 = acc0, acc2 = acc0, acc3 = acc0;
#pragma unroll
    for (int kc = 0; kc < 8; kc++) {
      acc0 = __builtin_amdgcn_mfma_f32_16x16x32_bf16(a[kc], bfrag[0][kc], acc0, 0, 0, 0);
      acc1 = __builtin_amdgcn_mfma_f32_16x16x32_bf16(a[kc], bfrag[1][kc], acc1, 0, 0, 0);
      acc2 = __builtin_amdgcn_mfma_f32_16x16x32_bf16(a[kc], bfrag[2][kc], acc2, 0, 0, 0);
      acc3 = __builtin_amdgcn_mfma_f32_16x16x32_bf16(a[kc], bfrag[3][kc], acc3, 0, 0, 0);
    }
#pragma unroll
    for (int r = 0; r < 4; r++) {
      const int row = (kq * 16 + lq * 4 + r) * 68;
      gpart[row + 0 * 16 + l15] = acc0[r];
      gpart[row + 1 * 16 + l15] = acc1[r];
      gpart[row + 2 * 16 + l15] = acc2[r];
      gpart[row + 3 * 16 + l15] = acc3[r];
    }
    __syncthreads();  // joint tag-validation cover (all 4 waves) + gpart ready

    float g0 = bf2f(xv0), g1 = bf2f(xv1), g2 = bf2f(xv2), g3 = bf2f(xv3);
#pragma unroll
    for (int q = 0; q < 4; q++) {
      const float* gp = &gpart[(q * 16 + eb) * 68 + ec];
      g0 += gp[0]; g1 += gp[16]; g2 += gp[32]; g3 += gp[48];
    }
    const float i_ = sigmoidf_(g0);
    const float f_ = sigmoidf_(g1);
    const float gg = tanhf_(g2);
    const float o_ = sigmoidf_(g3);
    c_state = f_ * c_state + i_ * gg;
    const float h = o_ * tanhf_(c_state);

    // tagged h' write-through to LLC: fire-and-forget (tag t+1 validates it)
    st4_llc(&hbuf32[(size_t)((t + 1) & 1) * (BATCH * HS) + (size_t)gb * HS +
                    j0 + ec],
            (((unsigned int)(t + 1)) << 16) | (unsigned int)f2bf(h));

    if (t == S_LEN - 1) {
      out[((size_t)gb * S_LEN + t) * HS + j0 + ec] = h;
      outh[gb * HS + j0 + ec] = h;
      outc[gb * HS + j0 + ec] = c_state;
      break;
    }

    // hint flag: fire-and-forget, NO store drain, NO barrier. Consumers
    // validate via tags; the flag only shortcuts their polling.
    if (tid == 0)
      st4_llc(&flags[wg * 16], (unsigned int)(t + 1));

    // out store: nontemporal, off the critical path (its ack drains inside
    // the next step's poll window).
    __builtin_nontemporal_store(h, &out[((size_t)gb * S_LEN + t) * HS + j0 + ec]);

    __syncthreads();  // gpart WAR across iterations

    xv0 = nx0; xv1 = nx1; xv2 = nx2; xv3 = nx3;
  }
}

// ------------------------------- launcher -----------------------------------
extern "C" void kernel_launch(void* const* d_in, const int* in_sizes, int n_in,
                              void* d_out, int out_size, void* d_ws,
                              size_t ws_size, hipStream_t stream) {
  const float* x  = (const float*)d_in[0];
  const float* wx = (const float*)d_in[1];
  const float* wh = (const float*)d_in[2];
  const float* bx = (const float*)d_in[3];
  const float* bh = (const float*)d_in[4];
  char* ws = (char*)d_ws;
  unsigned short* xg2  = (unsigned short*)(ws + XG2_OFF);
  unsigned short* xbf  = (unsigned short*)(ws + XBF_OFF);
  unsigned short* wxbf = (unsigned short*)(ws + WXBF_OFF);
  unsigned short* whbf = (unsigned short*)(ws + WHBF_OFF);
  unsigned int*   hbuf32 = (unsigned int*)(ws + HBUF32_OFF);
  int* flags = (int*)(ws + FLAG_OFF);

  float* out  = (float*)d_out;
  float* outh = out + (size_t)BATCH * S_LEN * HS;
  float* outc = outh + BATCH * HS;

  cvt_kernel<<<(33554432 / 4) / 256, 256, 0, stream>>>(x, xbf, 33554432 / 4);
  cvt_kernel<<<(4194304 / 4) / 256, 256, 0, stream>>>(wx, wxbf, 4194304 / 4);
  cvt_kernel<<<(4194304 / 4) / 256, 256, 0, stream>>>(wh, whbf, 4194304 / 4);
  // flags zeroed early (nothing touches them until lstm)
  zero_kernel<<<16, 256, 0, stream>>>((unsigned int*)flags, 4096);

  dim3 pg(HID / 128, (BATCH * S_LEN) / 128);  // 32 x 256
  pregemm_kernel<<<pg, 256, 0, stream>>>(xbf, wxbf, bx, bh, xg2);

  // zero tagged hbuf (131072 dwords) AFTER pregemm: it aliases the first
  // 512 KB of the (now dead) xbf region. Stream order guarantees safety.
  zero_kernel<<<(131072 + 255) / 256, 256, 0, stream>>>(hbuf32, 131072);

  lstm_kernel<<<256, 256, 0, stream>>>(whbf, xg2, hbuf32, flags, out, outh,
                                       outc);
}

// Round 5
// 2130.434 us; speedup vs baseline: 1.2502x; 1.1583x over previous
//
#include <hip/hip_runtime.h>
#include <hip/hip_bf16.h>
#include <stdint.h>

// ---------------------------------------------------------------------------
// LSTM: B=64, S=512, D_IN=1024, HID=4096, HS=1024, fp32 in/out.
//   1) cvt x, wx, wh -> bf16
//   2) pregemm (MFMA bf16, 128x128 tile): xg2 = x@wx.T + bx + bh, bf16,
//      recurrence-friendly layout [t][wg][bloc][n]  (identical to R3)
//   3) persistent recurrent kernel, R8: PER-WAVE FLAGS + off-chain out/xg.
//      R3 decomposition (4 groups x 16 batches x 64 slices, wh register-
//      resident, 2B bf16 h via sc0+sc1 LLC transport -- R6/R7's tagged-dword
//      experiment measured SLOWER, reverted). Chain deletions vs R3:
//      (a) per-WAVE flags: each wave drains ONLY its own h' stores
//          (vmcnt(0)) and publishes its own flag -- no intra-WG barrier,
//          no slowest-wave wait in the publish path. Consumer wave polls
//          its 16 producers x 4 waves = 64 flags, one per lane.
//      (b) out store (nontemporal HBM) moved AFTER the flag publish; its
//          ack drains inside the next step's poll window.
//      (c) xg2 for step t+1 prefetched at end of step t, issued after the
//          flag publish -- off both the consumer chain and the publish drain.
//      Safety (R3 proof, per-wave refinement): wave-flag >= t implies that
//      wave passed its WG's step-(t-1) barrier-1 (=> its WG finished ALL
//      h[t-1] reads) and its own h[t] stores are LLC-visible. The 4 consumer
//      waves' flag sets jointly cover all 256 producer-waves of the group
//      and join at barrier-1 before any h' write => WAR+RAW safe. Barrier-2
//      (gpart WAR) sits after the publish, off the critical path.
// R3 fix retained: register-tied s_waitcnt between asm h-loads and MFMA use.
// ---------------------------------------------------------------------------

typedef __attribute__((ext_vector_type(8))) short short8;
typedef __attribute__((ext_vector_type(4))) float floatx4;

#define S_LEN 512
#define BATCH 64
#define DIN   1024
#define HID   4096
#define HS    1024

// workspace byte offsets (total ~336.3 MB, same footprint as R3)
#define XG2_OFF   0ull                      // ushort[512*256*16*64] = 256 MB
#define XBF_OFF   268435456ull              // ushort[32768*1024]    = 64 MB
#define WXBF_OFF  335544320ull              // ushort[4096*1024]     = 8 MB
#define WHBF_OFF  343932928ull              // ushort[4096*1024]     = 8 MB
#define HBUF_OFF  352321536ull              // ushort[2][64][1024]   = 256 KB
// per-wave flags: int[256*4][16] = 64 KB, aliases the FIRST 64 KB of the
// xbf region (xbf is dead after pregemm; zeroed after pregemm runs).
#define FLAG_OFF  XBF_OFF

__device__ __forceinline__ unsigned short f2bf(float f) {
  unsigned int u = __float_as_uint(f);
  u += 0x7fffu + ((u >> 16) & 1u);        // RNE
  return (unsigned short)(u >> 16);
}
__device__ __forceinline__ float bf2f(unsigned short s) {
  return __uint_as_float(((unsigned int)s) << 16);
}

__device__ __forceinline__ void async_ld16(const void* g, const void* l) {
  __builtin_amdgcn_global_load_lds(
      (const __attribute__((address_space(1))) unsigned int*)g,
      (__attribute__((address_space(3))) unsigned int*)l,
      16, 0, 0);
}

// L2-bypassing (sc0 sc1) 16B load -> straight from LLC (writers wrote through)
__device__ __forceinline__ short8 load16_llc(const void* p) {
  floatx4 r;
  asm volatile("global_load_dwordx4 %0, %1, off sc0 sc1"
               : "=v"(r) : "v"(p) : "memory");
  return __builtin_bit_cast(short8, r);
}
// L2-bypassing 2B store (write-through to LLC).
__device__ __forceinline__ void store2_llc(void* p, unsigned int v) {
  asm volatile("global_store_short %0, %1, off sc0 sc1"
               :: "v"(p), "v"(v) : "memory");
}
// L2-bypassing dword store (flag publish).
__device__ __forceinline__ void st4_llc(void* p, unsigned int v) {
  asm volatile("global_store_dword %0, %1, off sc0 sc1"
               :: "v"(p), "v"(v) : "memory");
}
// L2-bypassing dword load with embedded drain (flag poll).
__device__ __forceinline__ int ld_flag_llc(const int* p) {
  int v;
  asm volatile("global_load_dword %0, %1, off sc0 sc1\n\t"
               "s_waitcnt vmcnt(0)"
               : "=v"(v) : "v"(p) : "memory");
  return v;
}

__device__ __forceinline__ float sigmoidf_(float x) {
  return 1.0f / (1.0f + __expf(-x));
}
__device__ __forceinline__ float tanhf_(float x) {
  return 2.0f / (1.0f + __expf(-2.0f * x)) - 1.0f;
}

// --------------------------- fp32 -> bf16 cast ------------------------------
__global__ void cvt_kernel(const float* __restrict__ src,
                           unsigned short* __restrict__ dst, int n4) {
  int i = blockIdx.x * blockDim.x + threadIdx.x;
  if (i < n4) {
    float4 v = ((const float4*)src)[i];
    ushort4 o;
    o.x = f2bf(v.x); o.y = f2bf(v.y); o.z = f2bf(v.z); o.w = f2bf(v.w);
    ((ushort4*)dst)[i] = o;
  }
}

__global__ void zero_kernel(unsigned int* __restrict__ p, int n) {
  int i = blockIdx.x * blockDim.x + threadIdx.x;
  if (i < n) p[i] = 0u;
}

// ------------------------------- pre-GEMM -----------------------------------
// C[m][g] = sum_k x_bf[m][k] * wx_bf[g][k] + bx[g] + bh[g]   (m = b*512 + t)
// stored bf16 at xg2[((t*256 + wg)*16 + bloc)*64 + n],
//   wg = (b>>4)*64 + ((g&1023)>>4),  bloc = b&15,  n = (g>>10)*16 + (g&15)
// (identical to R3's proven kernel)
__global__ __launch_bounds__(256) void pregemm_kernel(
    const unsigned short* __restrict__ A,    // [32768][1024] bf16
    const unsigned short* __restrict__ Bw,   // [4096][1024]  bf16 (B^T layout)
    const float* __restrict__ bx, const float* __restrict__ bh,
    unsigned short* __restrict__ xg2) {
  __shared__ unsigned short As[128 * 32];
  __shared__ unsigned short Bs[128 * 32];
  const int tid = threadIdx.x;
  const int lane = tid & 63, wv = tid >> 6;
  const int l15 = lane & 15, lq = lane >> 4;
  const int m0 = blockIdx.y * 128, n0 = blockIdx.x * 128;
  const int wm = (wv >> 1) * 64, wn = (wv & 1) * 64;

  floatx4 acc[4][4];
#pragma unroll
  for (int i = 0; i < 4; i++)
#pragma unroll
    for (int j = 0; j < 4; j++) acc[i][j] = (floatx4){0.f, 0.f, 0.f, 0.f};

  for (int k0 = 0; k0 < DIN; k0 += 32) {
#pragma unroll
    for (int q = 0; q < 2; q++) {
      const int e = (q * 256 + tid) * 8;      // element within 128x32 tile
      const int r = e >> 5, c = e & 31;
      async_ld16(A + (size_t)(m0 + r) * DIN + k0 + c, (unsigned short*)As + e);
      async_ld16(Bw + (size_t)(n0 + r) * DIN + k0 + c, (unsigned short*)Bs + e);
    }
    __syncthreads();
    short8 af[4], bfv[4];
#pragma unroll
    for (int i = 0; i < 4; i++)
      af[i] = *(const short8*)&As[(wm + i * 16 + l15) * 32 + lq * 8];
#pragma unroll
    for (int j = 0; j < 4; j++)
      bfv[j] = *(const short8*)&Bs[(wn + j * 16 + l15) * 32 + lq * 8];
#pragma unroll
    for (int i = 0; i < 4; i++)
#pragma unroll
      for (int j = 0; j < 4; j++)
        acc[i][j] = __builtin_amdgcn_mfma_f32_16x16x32_bf16(af[i], bfv[j],
                                                            acc[i][j], 0, 0, 0);
    __syncthreads();
  }

#pragma unroll
  for (int j = 0; j < 4; j++) {
    const int col = n0 + wn + j * 16 + l15;
    const float bias = bx[col] + bh[col];
    const int gate = col >> 10;
    const int c1 = col & 1023;
    const int wslice = c1 >> 4, cc = c1 & 15;
    const int n_idx = gate * 16 + cc;
#pragma unroll
    for (int i = 0; i < 4; i++) {
#pragma unroll
      for (int r = 0; r < 4; r++) {
        const int m = m0 + wm + i * 16 + lq * 4 + r;
        const int b = m >> 9, t = m & 511;
        const size_t idx =
            ((size_t)(t * 256 + ((b >> 4) * 64 + wslice)) * 16 + (b & 15)) * 64 +
            n_idx;
        xg2[idx] = f2bf(acc[i][j][r] + bias);
      }
    }
  }
}

// ------------------------------ recurrence ----------------------------------
// 256 WGs = 4 groups x 64 slices (R3 decomposition). Group g handles batches
// [g*16, g*16+16). WG slice w holds wh rows {gate*1024 + w*16 + c} in
// registers (4 waves split K: wave kq holds k in [kq*256, kq*256+256)).
// Wave kq of WG w produces h' for batches [g*16+kq*4, +4), cols [w*16,+16),
// and publishes wave-flag (w,kq) after draining ONLY its own stores.
__global__ __launch_bounds__(256, 1) void lstm_kernel(
    const unsigned short* __restrict__ whbf,  // [4096][1024] bf16
    const unsigned short* __restrict__ xg2,
    unsigned short* __restrict__ hbuf,        // [2][64][1024] bf16
    int* __restrict__ flags,                  // [256*4][16] wave-flags
    float* __restrict__ out,                  // [64][512][1024]
    float* __restrict__ outh, float* __restrict__ outc) {
  __shared__ float gpart[4 * 16 * 68];  // [kq][bloc][n] padded

  const int tid = threadIdx.x;
  const int lane = tid & 63, kq = tid >> 6;
  const int l15 = lane & 15, lq = lane >> 4;
  const int wg = blockIdx.x;
  const int group = wg >> 6, wslice = wg & 63;
  const int j0 = wslice * 16;

  // B fragments: bfrag[j][kc] covers gate j, cols j0..j0+15, k = kq*256+kc*32+..
  short8 bfrag[4][8];
#pragma unroll
  for (int j = 0; j < 4; j++) {
    const size_t grow = (size_t)(j * 1024 + j0 + l15) * HS;
#pragma unroll
    for (int kc = 0; kc < 8; kc++)
      bfrag[j][kc] = *(const short8*)&whbf[grow + kq * 256 + kc * 32 + lq * 8];
  }

  const int eb = tid >> 4;         // bloc 0..15 (elementwise phase)
  const int ec = tid & 15;         // col within slice
  const int gb = group * 16 + eb;  // global batch
  float c_state = 0.0f;

  // h-load base: batch group*16+l15, col kq*256 + lq*8 (+kc*32)
  const size_t arow = (size_t)(group * 16 + l15) * HS + kq * 256 + lq * 8;
  // wave kq consumes h cols [kq*256,+256) -> producer WGs kq*16..+16, all 4
  // waves each: lane polls producer WG (lane>>2), wave (lane&3).
  const int* fp = flags +
      ((size_t)((group * 64 + kq * 16 + (lane >> 2)) * 4 + (lane & 3))) * 16;

  // xg for t=0 (plain cached loads; compiler waits at first use)
  const unsigned short* xr0 = xg2 + ((size_t)(0 * 256 + wg) * 16 + eb) * 64 + ec;
  unsigned short xv0 = xr0[0], xv1 = xr0[16], xv2 = xr0[32], xv3 = xr0[48];

  for (int t = 0; t < S_LEN; t++) {
    if (t > 0) {
      // all 64 lanes poll (one wave-flag each); first round's embedded
      // vmcnt(0) also absorbs last step's out-store ack + xg prefetch.
      while (true) {
        int v = ld_flag_llc(fp);
        if (__all(v >= t)) break;
        __builtin_amdgcn_s_sleep(1);
      }
    }

    // h loads: sc0+sc1 direct from LLC (writers wrote through)
    const unsigned short* hp = hbuf + (size_t)(t & 1) * (BATCH * HS) + arow;
    short8 a[8];
#pragma unroll
    for (int kc = 0; kc < 8; kc++) a[kc] = load16_llc(&hp[kc * 32]);
    // Register-tied drain: MFMA below data-depends on these operands, so it
    // cannot be scheduled above this waitcnt (R2's NaN bug).
    asm volatile("s_waitcnt vmcnt(0)"
                 : "+v"(a[0]), "+v"(a[1]), "+v"(a[2]), "+v"(a[3]),
                   "+v"(a[4]), "+v"(a[5]), "+v"(a[6]), "+v"(a[7])
                 :: "memory");

    floatx4 acc0 = (floatx4){0.f, 0.f, 0.f, 0.f};
    floatx4 acc1 = acc0, acc2 = acc0, acc3 = acc0;
#pragma unroll
    for (int kc = 0; kc < 8; kc++) {
      acc0 = __builtin_amdgcn_mfma_f32_16x16x32_bf16(a[kc], bfrag[0][kc], acc0, 0, 0, 0);
      acc1 = __builtin_amdgcn_mfma_f32_16x16x32_bf16(a[kc], bfrag[1][kc], acc1, 0, 0, 0);
      acc2 = __builtin_amdgcn_mfma_f32_16x16x32_bf16(a[kc], bfrag[2][kc], acc2, 0, 0, 0);
      acc3 = __builtin_amdgcn_mfma_f32_16x16x32_bf16(a[kc], bfrag[3][kc], acc3, 0, 0, 0);
    }
#pragma unroll
    for (int r = 0; r < 4; r++) {
      const int row = (kq * 16 + lq * 4 + r) * 68;
      gpart[row + 0 * 16 + l15] = acc0[r];
      gpart[row + 1 * 16 + l15] = acc1[r];
      gpart[row + 2 * 16 + l15] = acc2[r];
      gpart[row + 3 * 16 + l15] = acc3[r];
    }
    __syncthreads();  // barrier 1: joint poll cover + gpart ready

    float g0 = bf2f(xv0), g1 = bf2f(xv1), g2 = bf2f(xv2), g3 = bf2f(xv3);
#pragma unroll
    for (int q = 0; q < 4; q++) {
      const float* gp = &gpart[(q * 16 + eb) * 68 + ec];
      g0 += gp[0]; g1 += gp[16]; g2 += gp[32]; g3 += gp[48];
    }
    const float i_ = sigmoidf_(g0);
    const float f_ = sigmoidf_(g1);
    const float gg = tanhf_(g2);
    const float o_ = sigmoidf_(g3);
    c_state = f_ * c_state + i_ * gg;
    const float h = o_ * tanhf_(c_state);

    // h' write-through to LLC (this thread's single element)
    store2_llc(&hbuf[(size_t)((t + 1) & 1) * (BATCH * HS) + (size_t)gb * HS +
                     j0 + ec],
               (unsigned int)f2bf(h));

    if (t == S_LEN - 1) {
      out[((size_t)gb * S_LEN + t) * HS + j0 + ec] = h;
      outh[gb * HS + j0 + ec] = h;
      outc[gb * HS + j0 + ec] = c_state;
      break;  // nobody waits on the last flag
    }

    // publish path: drain THIS WAVE's h' stores only, then wave-flag.
    // (asm volatile + memory clobber keeps store->wait->flag program order)
    asm volatile("s_waitcnt vmcnt(0)" ::: "memory");
    if (lane == 0)
      st4_llc(&flags[(wg * 4 + kq) * 16], (unsigned int)(t + 1));

    // xg prefetch for t+1: issued AFTER the publish (off the publish drain;
    // returns during the next poll window). t+1 <= 511, always in-bounds.
    const unsigned short* xb =
        xg2 + ((size_t)((t + 1) * 256 + wg) * 16 + eb) * 64 + ec;
    unsigned short nx0 = xb[0], nx1 = xb[16], nx2 = xb[32], nx3 = xb[48];

    // out store: nontemporal, off the critical path (ack drains inside the
    // next step's poll round).
    __builtin_nontemporal_store(h, &out[((size_t)gb * S_LEN + t) * HS + j0 + ec]);

    __syncthreads();  // barrier 2: gpart WAR across iterations (off-chain)

    xv0 = nx0; xv1 = nx1; xv2 = nx2; xv3 = nx3;
  }
}

// ------------------------------- launcher -----------------------------------
extern "C" void kernel_launch(void* const* d_in, const int* in_sizes, int n_in,
                              void* d_out, int out_size, void* d_ws,
                              size_t ws_size, hipStream_t stream) {
  const float* x  = (const float*)d_in[0];
  const float* wx = (const float*)d_in[1];
  const float* wh = (const float*)d_in[2];
  const float* bx = (const float*)d_in[3];
  const float* bh = (const float*)d_in[4];
  char* ws = (char*)d_ws;
  unsigned short* xg2  = (unsigned short*)(ws + XG2_OFF);
  unsigned short* xbf  = (unsigned short*)(ws + XBF_OFF);
  unsigned short* wxbf = (unsigned short*)(ws + WXBF_OFF);
  unsigned short* whbf = (unsigned short*)(ws + WHBF_OFF);
  unsigned short* hbuf = (unsigned short*)(ws + HBUF_OFF);
  int* flags = (int*)(ws + FLAG_OFF);

  float* out  = (float*)d_out;
  float* outh = out + (size_t)BATCH * S_LEN * HS;
  float* outc = outh + BATCH * HS;

  cvt_kernel<<<(33554432 / 4) / 256, 256, 0, stream>>>(x, xbf, 33554432 / 4);
  cvt_kernel<<<(4194304 / 4) / 256, 256, 0, stream>>>(wx, wxbf, 4194304 / 4);
  cvt_kernel<<<(4194304 / 4) / 256, 256, 0, stream>>>(wh, whbf, 4194304 / 4);
  // zero hbuf (65536 uints) early -- its region is untouched until lstm
  zero_kernel<<<256, 256, 0, stream>>>((unsigned int*)(ws + HBUF_OFF), 65536);

  dim3 pg(HID / 128, (BATCH * S_LEN) / 128);  // 32 x 256
  pregemm_kernel<<<pg, 256, 0, stream>>>(xbf, wxbf, bx, bh, xg2);

  // zero per-wave flags (16384 uints = 64 KB) AFTER pregemm: they alias the
  // first 64 KB of the (now dead) xbf region. Stream order guarantees safety.
  zero_kernel<<<64, 256, 0, stream>>>((unsigned int*)flags, 16384);

  lstm_kernel<<<256, 256, 0, stream>>>(whbf, xg2, hbuf, flags, out, outh, outc);
}